// Round 1
// 244.488 us; speedup vs baseline: 1.0322x; 1.0322x over previous
//
#include <hip/hip_runtime.h>
#include <stdint.h>

typedef unsigned short us16;
typedef unsigned short us8  __attribute__((ext_vector_type(8)));
typedef unsigned short us4v __attribute__((ext_vector_type(4)));
typedef __bf16         bf16x8 __attribute__((ext_vector_type(8)));
typedef float          f32x4  __attribute__((ext_vector_type(4)));

__device__ __forceinline__ us16 f2bf(float f) {
    union { float f; unsigned int u; } c; c.f = f;
    unsigned int u = (c.u + 0x7fffu + ((c.u >> 16) & 1u)) >> 16;
    return (us16)u;
}

// async global->LDS, 16 B per lane; LDS dest = wave-uniform base + lane*16
__device__ __forceinline__ void async16(const us16* g, us16* l) {
    __builtin_amdgcn_global_load_lds(
        (const __attribute__((address_space(1))) unsigned int*)g,
        (__attribute__((address_space(3))) unsigned int*)l,
        16, 0, 0);
}

// counted vmcnt wait (T4): never 0 in the steady-state loop
template <int N> __device__ __forceinline__ void wait_vm() {
    if constexpr (N == 8)      asm volatile("s_waitcnt vmcnt(8)" ::: "memory");
    else if constexpr (N == 6) asm volatile("s_waitcnt vmcnt(6)" ::: "memory");
    else if constexpr (N == 4) asm volatile("s_waitcnt vmcnt(4)" ::: "memory");
    else if constexpr (N == 3) asm volatile("s_waitcnt vmcnt(3)" ::: "memory");
    else                       asm volatile("s_waitcnt vmcnt(0)" ::: "memory");
}

// ---------------------------------------------------------------------------
// Pipelined GEMM core (T3+T4+T5 on top of the R4-proven swizzle):
//   C[n][m] = sum_k A[m][k]*B[n][k], ldC = M.
//   8 waves (2 M x 4 N), 512 threads. BM = 32*MI, BN = 64*NJ.
//   BK=32, 4-deep LDS ring: at tile t stage tile t+3, compute tile t,
//   then counted vmcnt(2*LD) + ONE raw s_barrier per tile (no drain).
// LDS rows are 64 B (4 x 16B chunks); chunk swizzle = c ^ (row&3) ^ ((row>>2)&3)
// (2-way on ds_read_b128 = free). global_load_lds writes linearly, so the
// inverse swizzle is folded into the per-lane GLOBAL source chunk gc.
// EPI: 0 bf16 store + bias[m] | 1 bf16 store + bias[n]
//      2 bf16 store of exp(acc/32) + atomicAdd row sums into L[n]
//      3 f32 store of acc * (1/L[n])
// ---------------------------------------------------------------------------
template <int EPI, int MI, int NJ>
__device__ __forceinline__ void gemm_pipe(
        const us16* __restrict__ A, const us16* __restrict__ B,
        void* __restrict__ C, const float* __restrict__ bias,
        float* __restrict__ L,
        int M, int K, int x, int y, us16* lds) {
    constexpr int BM  = 32 * MI;       // 2 waves * MI frags * 16
    constexpr int BN  = 64 * NJ;       // 4 waves * NJ frags * 16
    constexpr int IA  = BM / 128;      // global_load_lds issues/thread for A per tile
    constexpr int IB  = BN / 128;
    constexpr int EA  = BM * 32;       // elems per A K-tile
    constexpr int BUF = EA + BN * 32;  // elems per ring slot (A + B)
    constexpr int LD  = IA + IB;       // loads/thread per tile

    const int tid  = threadIdx.x;
    const int lane = tid & 63, wid = tid >> 6;
    const int l15  = lane & 15, quad = lane >> 4;
    const int wm   = wid >> 2, wn = wid & 3;       // 2 x 4 wave grid
    const int m0   = x * BM, n0 = y * BN;

    // staging: issue covers 16 rows (lane>>2 = row, lane&3 = stored chunk);
    // source chunk pre-swizzled so LDS ends up swizzle(row)-consistent.
    const int gc8  = (((lane & 3) ^ ((lane >> 2) & 3) ^ ((lane >> 4) & 3))) * 8;
    const int lsub = lane >> 2;

    const us16* Ag[IA]; int Al[IA];
#pragma unroll
    for (int c = 0; c < IA; c++) {
        const int r = wid * (16 * IA) + c * 16;
        Ag[c] = A + (size_t)(m0 + r + lsub) * K + gc8;
        Al[c] = r * 32;
    }
    const us16* Bg[IB]; int Bl[IB];
#pragma unroll
    for (int c = 0; c < IB; c++) {
        const int r = wid * (16 * IB) + c * 16;
        Bg[c] = B + (size_t)(n0 + r + lsub) * K + gc8;
        Bl[c] = EA + r * 32;
    }

    const int NT  = K >> 5;
    // read chunk: quad ^ swizzle(row); row&3 = l15&3, (row>>2)&3 = (l15>>2)&3
    const int rc8    = ((quad ^ (l15 & 3) ^ ((l15 >> 2) & 3))) * 8;
    const int raBase = wm * (MI * 16) + l15;
    const int rbBase = wn * (NJ * 16) + l15;

    f32x4 acc[MI][NJ] = {};

    // prologue: stage tiles 0..2 into slots 0..2, wait tile0 landed (2*LD left)
#pragma unroll
    for (int t = 0; t < 3; t++) {
        us16* bp = lds + t * BUF;
        const int ko = t * 32;
#pragma unroll
        for (int c = 0; c < IA; c++) async16(Ag[c] + ko, bp + Al[c]);
#pragma unroll
        for (int c = 0; c < IB; c++) async16(Bg[c] + ko, bp + Bl[c]);
    }
    wait_vm<2 * LD>();
    __builtin_amdgcn_s_barrier();

    for (int t = 0; t < NT; t++) {
        // stage tile t+3 into slot (t+3)&3 (= slot read at t-1: safe past barrier)
        if (t + 3 < NT) {
            us16* bp = lds + ((t + 3) & 3) * BUF;
            const int ko = (t + 3) * 32;
#pragma unroll
            for (int c = 0; c < IA; c++) async16(Ag[c] + ko, bp + Al[c]);
#pragma unroll
            for (int c = 0; c < IB; c++) async16(Bg[c] + ko, bp + Bl[c]);
        }
        const us16* bp = lds + (t & 3) * BUF;
        bf16x8 af[MI], bfv[NJ];
#pragma unroll
        for (int i = 0; i < MI; i++)
            af[i]  = *(const bf16x8*)(bp + (raBase + i * 16) * 32 + rc8);
#pragma unroll
        for (int j = 0; j < NJ; j++)
            bfv[j] = *(const bf16x8*)(bp + EA + (rbBase + j * 16) * 32 + rc8);
        __builtin_amdgcn_s_setprio(1);
#pragma unroll
        for (int i = 0; i < MI; i++)
#pragma unroll
            for (int j = 0; j < NJ; j++)
                acc[i][j] = __builtin_amdgcn_mfma_f32_16x16x32_bf16(af[i], bfv[j], acc[i][j], 0, 0, 0);
        __builtin_amdgcn_s_setprio(0);
        // need tile t+1 landed; allow tiles t+2,t+3 to stay in flight (counted)
        if (t + 3 < NT)      wait_vm<2 * LD>();
        else if (t + 2 < NT) wait_vm<LD>();
        else if (t + 1 < NT) wait_vm<0>();
        __builtin_amdgcn_sched_barrier(0);   // pin: nothing crosses the barrier
        __builtin_amdgcn_s_barrier();
    }

    if (EPI == 2) {
        const float scale = 0.03125f;
        float rs[NJ];
#pragma unroll
        for (int j = 0; j < NJ; j++) rs[j] = 0.f;
#pragma unroll
        for (int i = 0; i < MI; i++) {
            const int mb = m0 + wm * (MI * 16) + i * 16 + quad * 4;
#pragma unroll
            for (int j = 0; j < NJ; j++) {
                const int n = n0 + wn * (NJ * 16) + j * 16 + l15;
                f32x4 v = acc[i][j];
                const float e0 = __expf(v[0] * scale), e1 = __expf(v[1] * scale);
                const float e2 = __expf(v[2] * scale), e3 = __expf(v[3] * scale);
                rs[j] += (e0 + e1) + (e2 + e3);
                us4v st = { f2bf(e0), f2bf(e1), f2bf(e2), f2bf(e3) };
                *(us4v*)((us16*)C + (size_t)n * M + mb) = st;
            }
        }
#pragma unroll
        for (int j = 0; j < NJ; j++) {
            rs[j] += __shfl_xor(rs[j], 16, 64);
            rs[j] += __shfl_xor(rs[j], 32, 64);
        }
        if (quad == 0) {
#pragma unroll
            for (int j = 0; j < NJ; j++)
                atomicAdd(&L[n0 + wn * (NJ * 16) + j * 16 + l15], rs[j]);
        }
        return;
    }

#pragma unroll
    for (int i = 0; i < MI; i++) {
        const int mb = m0 + wm * (MI * 16) + i * 16 + quad * 4;
        float b0 = 0.f, b1 = 0.f, b2 = 0.f, b3 = 0.f;
        if (EPI == 0) {
            float4 bv4 = *(const float4*)(bias + mb);
            b0 = bv4.x; b1 = bv4.y; b2 = bv4.z; b3 = bv4.w;
        }
#pragma unroll
        for (int j = 0; j < NJ; j++) {
            const int n = n0 + wn * (NJ * 16) + j * 16 + l15;
            f32x4 v = acc[i][j];
            if (EPI == 3) {
                const float inv = 1.0f / L[n];
                float4 st;
                st.x = v[0] * inv; st.y = v[1] * inv;
                st.z = v[2] * inv; st.w = v[3] * inv;
                *(float4*)((float*)C + (size_t)n * M + mb) = st;
            } else {
                const float bn = (EPI == 1) ? bias[n] : 0.0f;
                us4v st = { f2bf(v[0] + b0 + bn), f2bf(v[1] + b1 + bn),
                            f2bf(v[2] + b2 + bn), f2bf(v[3] + b3 + bn) };
                *(us4v*)((us16*)C + (size_t)n * M + mb) = st;
            }
        }
    }
}

// strip swizzle: lin in [0, gx*gy), strips of 4 m-panels (gx % 4 == 0).
// Same-XCD subsequences (stride 8) stay within a 4-A-panel strip -> L2 reuse.
__device__ __forceinline__ void strip_xy(int lin, int gy, int& x, int& y) {
    const int within = lin & (4 * gy - 1);   // gy is pow2
    x = (lin / (4 * gy)) * 4 + (within & 3);
    y = within >> 2;
}

// ---------------------------------------------------------------------------
// prep: id<2048 -> transpose x [B][D][S] f32 -> XT [B][S][D] bf16 (64x64 tile)
//       id>=2048 -> convert Wq/Wk/Wv f32 -> Wb bf16 [3][1024][1024]
// ---------------------------------------------------------------------------
__global__ __launch_bounds__(256)
void prep(const float* __restrict__ x, us16* __restrict__ xt,
          const float* __restrict__ wq, const float* __restrict__ wk,
          const float* __restrict__ wv, us16* __restrict__ wb) {
    __shared__ us16 tile[64 * 65];
    const int id = blockIdx.x;
    const int t = threadIdx.x;
    if (id < 2048) {
        const int s0 = (id & 31) * 64, d0 = ((id >> 5) & 15) * 64, b = id >> 9;
        const float* xp = x + ((size_t)b * 1024 + d0) * 2048 + s0;
        const int r = t >> 4, c4 = t & 15;
#pragma unroll
        for (int i = 0; i < 4; i++) {
            float4 v = *(const float4*)(xp + (size_t)(r + 16 * i) * 2048 + c4 * 4);
            const int d = r + 16 * i;
            tile[(c4 * 4 + 0) * 65 + d] = f2bf(v.x);
            tile[(c4 * 4 + 1) * 65 + d] = f2bf(v.y);
            tile[(c4 * 4 + 2) * 65 + d] = f2bf(v.z);
            tile[(c4 * 4 + 3) * 65 + d] = f2bf(v.w);
        }
        __syncthreads();
        us16* op = xt + ((size_t)b * 2048 + s0) * 1024 + d0;
#pragma unroll
        for (int i = 0; i < 2; i++) {
            const int u = t + 256 * i;
            const int s = u >> 3, c8 = u & 7;
            us8 o;
#pragma unroll
            for (int j = 0; j < 8; j++) o[j] = tile[s * 65 + c8 * 8 + j];
            *(us8*)(op + (size_t)s * 1024 + c8 * 8) = o;
        }
    } else {
        const int cid = id - 2048;                  // 0..3071
        const int mb = cid >> 10;
        const float* src = (mb == 0) ? wq : (mb == 1) ? wk : wv;
        const size_t off = ((size_t)(cid & 1023) * 256 + t) * 4;
        float4 v = *(const float4*)(src + off);
        us4v o = { f2bf(v.x), f2bf(v.y), f2bf(v.z), f2bf(v.w) };
        *(us4v*)(wb + (size_t)mb * 1048576 + off) = o;
    }
}

// ---------------------------------------------------------------------------
// qkv: one dispatch, 512 blocks of 512 threads (2 clean waves at 1 block/CU).
//  id < 256 : Q/K at 256x256. z=id>>5 (0..3 Q, 4..7 K), grid 4(m=e) x 8(n=s)
//  id >= 256: V   at 128x256. z=(id-256)>>6, grid 16(m=s) x 4(n=e) -> VT [e][s]
// ---------------------------------------------------------------------------
__global__ __launch_bounds__(512)
void qkv(const us16* __restrict__ Wb, const us16* __restrict__ XT,
         us16* __restrict__ Qb, us16* __restrict__ Kb, us16* __restrict__ VT,
         const float* __restrict__ bq, const float* __restrict__ bk,
         const float* __restrict__ bv) {
    __shared__ __align__(16) us16 lds[65536];   // 128 KiB: 4-slot ring
    const int id = blockIdx.x;
    const long long sXT = 2097152;   // S*D
    if (id < 256) {
        const int z = id >> 5, zz = z & 3;
        const bool isK = z >= 4;
        int x, y; strip_xy(id & 31, 8, x, y);
        const us16* A = Wb + (isK ? 1048576 : 0);
        const us16* B = XT + (size_t)zz * sXT;
        us16* C = (isK ? Kb : Qb) + (size_t)zz * sXT;
        gemm_pipe<0, 8, 4>(A, B, (void*)C, isK ? bk : bq, nullptr,
                           1024, 1024, x, y, lds);
    } else {
        const int id2 = id - 256;
        const int z = id2 >> 6;
        int x, y; strip_xy(id2 & 63, 4, x, y);
        gemm_pipe<1, 4, 4>(XT + (size_t)z * sXT, Wb + 2097152,
                           (void*)(VT + (size_t)z * sXT), bv, nullptr,
                           2048, 1024, x, y, lds);
    }
}

// ---------------------------------------------------------------------------
// scores: P~[b][s][t] = exp(q_s.k_t/32), plus L[b][s] = sum_t P~ (atomics)
// A=K (m=t), B=Q (n=s), 256x256 tile, grid (8,8,4) = 256 blocks (1 wave)
// ---------------------------------------------------------------------------
__global__ __launch_bounds__(512)
void scores_k(const us16* __restrict__ Kb, const us16* __restrict__ Qb,
              us16* __restrict__ Sb, float* __restrict__ L) {
    __shared__ __align__(16) us16 lds[65536];
    const long long sXT = 2097152, sSS = 4194304;
    const int z = blockIdx.z;
    int x, y; strip_xy(blockIdx.x + 8 * blockIdx.y, 8, x, y);
    gemm_pipe<2, 8, 4>(Kb + (size_t)z * sXT, Qb + (size_t)z * sXT,
                       (void*)(Sb + (size_t)z * sSS), nullptr, L + z * 2048,
                       2048, 1024, x, y, lds);
}

// ---------------------------------------------------------------------------
// out: out[b][s][e] = (sum_t P~[s][t] v[t][e]) / L[b][s]
// A=VT (m=e), B=P~ (n=s), 128x256 tile, grid (8,8,4) = 256 blocks (1 wave)
// ---------------------------------------------------------------------------
__global__ __launch_bounds__(512)
void out_k(const us16* __restrict__ VT, const us16* __restrict__ Sb,
           float* __restrict__ L, float* __restrict__ out) {
    __shared__ __align__(16) us16 lds[49152];   // 96 KiB ring (128x256 tile)
    const long long sXT = 2097152, sSS = 4194304;
    const int z = blockIdx.z;
    int x, y; strip_xy(blockIdx.x + 8 * blockIdx.y, 8, x, y);
    gemm_pipe<3, 4, 4>(VT + (size_t)z * sXT, Sb + (size_t)z * sSS,
                       (void*)(out + (size_t)z * sXT), nullptr, L + z * 2048,
                       1024, 2048, x, y, lds);
}

// ---------------------------------------------------------------------------
extern "C" void kernel_launch(void* const* d_in, const int* in_sizes, int n_in,
                              void* d_out, int out_size, void* d_ws, size_t ws_size,
                              hipStream_t stream) {
    const float* x  = (const float*)d_in[0];
    const float* Wq = (const float*)d_in[1];
    const float* bq = (const float*)d_in[2];
    const float* Wk = (const float*)d_in[3];
    const float* bk = (const float*)d_in[4];
    const float* Wv = (const float*)d_in[5];
    const float* bv = (const float*)d_in[6];
    float* out = (float*)d_out;
    char* ws = (char*)d_ws;

    const size_t SZ = 16777216;   // B*S*D bf16
    us16* Qb = (us16*)(ws);
    us16* Kb = (us16*)(ws + SZ);
    us16* VT = (us16*)(ws + 2 * SZ);            // [B][D][S]
    us16* XT = (us16*)(ws + 3 * SZ);            // [B][S][D]
    us16* Wb = (us16*)(ws + 4 * SZ);            // [3][1024][1024]
    us16* Sb = (us16*)(ws + 3 * SZ);            // P~ [B][S][S], aliases dead XT/Wb
    float* Lb = (float*)(ws + 5 * SZ);          // L [B][S] fp32 at 80 MiB

    hipMemsetAsync(Lb, 0, 4 * 2048 * sizeof(float), stream);
    prep<<<dim3(5120, 1, 1), dim3(256, 1, 1), 0, stream>>>(x, XT, Wq, Wk, Wv, Wb);
    qkv<<<dim3(512, 1, 1), dim3(512, 1, 1), 0, stream>>>(Wb, XT, Qb, Kb, VT, bq, bk, bv);
    scores_k<<<dim3(8, 8, 4), dim3(512, 1, 1), 0, stream>>>(Kb, Qb, Sb, Lb);
    out_k<<<dim3(8, 8, 4), dim3(512, 1, 1), 0, stream>>>(VT, Sb, Lb, out);
}

// Round 2
// 239.882 us; speedup vs baseline: 1.0520x; 1.0192x over previous
//
#include <hip/hip_runtime.h>
#include <stdint.h>

typedef unsigned short us16;
typedef unsigned short us8  __attribute__((ext_vector_type(8)));
typedef unsigned short us4v __attribute__((ext_vector_type(4)));
typedef __bf16         bf16x8 __attribute__((ext_vector_type(8)));
typedef float          f32x4  __attribute__((ext_vector_type(4)));

__device__ __forceinline__ us16 f2bf(float f) {
    union { float f; unsigned int u; } c; c.f = f;
    unsigned int u = (c.u + 0x7fffu + ((c.u >> 16) & 1u)) >> 16;
    return (us16)u;
}

// async global->LDS, 16 B per lane; LDS dest = wave-uniform base + lane*16
__device__ __forceinline__ void async16(const us16* g, us16* l) {
    __builtin_amdgcn_global_load_lds(
        (const __attribute__((address_space(1))) unsigned int*)g,
        (__attribute__((address_space(3))) unsigned int*)l,
        16, 0, 0);
}

// counted vmcnt wait (T4): never 0 in the steady-state loop
template <int N> __device__ __forceinline__ void wait_vm() {
    if constexpr (N == 8)      asm volatile("s_waitcnt vmcnt(8)" ::: "memory");
    else if constexpr (N == 6) asm volatile("s_waitcnt vmcnt(6)" ::: "memory");
    else                       asm volatile("s_waitcnt vmcnt(0)" ::: "memory");
}

// ---------------------------------------------------------------------------
// GEMM core v3: C[n][m] = sum_k A[m][k]*B[n][k], ldC = M.
//  Tile BM x 256 (BM = MI*32), BK = 64, 8 waves (2 M x 4 N), 512 threads.
//  LDS: 2 whole-tile buffers; rows are 128 B (64 bf16), phys chunk =
//  logical ^ (row&7)  -- the R0-proven zero-conflict swizzle, applied
//  both-sides (pre-swizzled global source, swizzled ds_read).
//  Pipeline: at tile t stage ALL of tile t+1 (ACALLS+4 calls/wave), then
//  counted vmcnt(NVM) waits exactly tile t's loads (t+1 stays in flight
//  across the whole tile), one entry barrier; 4 phases of
//  {A ds_reads -> 16*PMI MFMA (setprio-wrapped) -> pinned s_barrier}.
//  B fragments are read once per tile and held in registers (32 VGPR).
// EPI: 0 bf16 store + bias[m] | 1 bf16 store + bias[n]
//      2 bf16 store of exp(acc/32) + atomicAdd row sums into L[n]
//      3 f32 store of acc * (1/L[n])
// ---------------------------------------------------------------------------
template <int EPI, int MI>
__device__ __forceinline__ void gemm_core(
        const us16* __restrict__ A, const us16* __restrict__ B,
        void* __restrict__ C, const float* __restrict__ bias,
        float* __restrict__ L,
        int M, int K, int x, int y, us16* lds) {
    constexpr int BM     = MI * 32;
    constexpr int BOFF   = BM * 64;            // B region offset (elems)
    constexpr int BUF    = (BM + 256) * 64;    // elems per buffer
    constexpr int ACALLS = BM / 64;            // 8KB stage calls for A
    constexpr int NVM    = ACALLS + 4;         // vm-ops per tile per wave
    constexpr int PMI    = MI / 4;             // A frag-rows per phase

    const int tid  = threadIdx.x;
    const int lane = tid & 63, wid = tid >> 6;
    const int l15  = lane & 15, quad = lane >> 4;
    const int wm   = wid >> 2, wn = wid & 3;   // 2 x 4 wave grid
    const int m0   = x * BM, n0 = y * 256;

    // staging: call covers 64 rows; thread t -> row t>>3, stored chunk t&7,
    // global chunk pre-swizzled (t&7)^(row&7). LDS dest linear = base+t*16B.
    const int srow = tid >> 3;
    const int sc   = ((tid & 7) ^ (srow & 7)) * 8;
    const us16* Ag = A + (size_t)(m0 + srow) * K + sc;
    const us16* Bg = B + (size_t)(n0 + srow) * K + sc;
    const int sl   = tid * 8;                  // elem offset within call

    f32x4 acc[MI][4] = {};
    const int NT = K >> 6;

    // prologue: stage tile 0 into buf 0
#pragma unroll
    for (int c = 0; c < ACALLS; c++) async16(Ag + (size_t)(c * 64) * K, lds + c * 4096 + sl);
#pragma unroll
    for (int c = 0; c < 4; c++)      async16(Bg + (size_t)(c * 64) * K, lds + BOFF + c * 4096 + sl);

    for (int t = 0; t < NT; t++) {
        const us16* cur = lds + (t & 1) * BUF;
        // stage all of tile t+1 into the other buffer, then counted wait
        if (t + 1 < NT) {
            us16* nxt = lds + ((t + 1) & 1) * BUF;
            const size_t ko = (size_t)(t + 1) * 64;
#pragma unroll
            for (int c = 0; c < ACALLS; c++) async16(Ag + (size_t)(c * 64) * K + ko, nxt + c * 4096 + sl);
#pragma unroll
            for (int c = 0; c < 4; c++)      async16(Bg + (size_t)(c * 64) * K + ko, nxt + BOFF + c * 4096 + sl);
            wait_vm<NVM>();          // tile t landed; t+1 stays in flight
        } else {
            wait_vm<0>();            // tail drain
        }
        __builtin_amdgcn_sched_barrier(0);
        __builtin_amdgcn_s_barrier();
        __builtin_amdgcn_sched_barrier(0);

        // B fragments: read once, held in registers across the tile
        bf16x8 bf[4][2];
#pragma unroll
        for (int nj = 0; nj < 4; nj++) {
            const int rb = wn * 64 + nj * 16 + l15;
#pragma unroll
            for (int ks = 0; ks < 2; ks++)
                bf[nj][ks] = *(const bf16x8*)(cur + BOFF + rb * 64 + ((ks * 4 + quad) ^ (rb & 7)) * 8);
        }
#pragma unroll
        for (int p = 0; p < 4; p++) {
            bf16x8 af[PMI][2];
#pragma unroll
            for (int i = 0; i < PMI; i++) {
                const int ra = wm * (MI * 16) + (p * PMI + i) * 16 + l15;
#pragma unroll
                for (int ks = 0; ks < 2; ks++)
                    af[i][ks] = *(const bf16x8*)(cur + ra * 64 + ((ks * 4 + quad) ^ (ra & 7)) * 8);
            }
            __builtin_amdgcn_s_setprio(1);
#pragma unroll
            for (int ks = 0; ks < 2; ks++)
#pragma unroll
                for (int i = 0; i < PMI; i++)
#pragma unroll
                    for (int nj = 0; nj < 4; nj++)
                        acc[p * PMI + i][nj] = __builtin_amdgcn_mfma_f32_16x16x32_bf16(
                            af[i][ks], bf[nj][ks], acc[p * PMI + i][nj], 0, 0, 0);
            __builtin_amdgcn_s_setprio(0);
            __builtin_amdgcn_sched_barrier(0);
            __builtin_amdgcn_s_barrier();
            __builtin_amdgcn_sched_barrier(0);
        }
    }

    if (EPI == 2) {
        const float scale = 0.03125f;
        float rs[4] = {0.f, 0.f, 0.f, 0.f};
#pragma unroll
        for (int i = 0; i < MI; i++) {
            const int mb = m0 + wm * (MI * 16) + i * 16 + quad * 4;
#pragma unroll
            for (int j = 0; j < 4; j++) {
                const int n = n0 + wn * 64 + j * 16 + l15;
                f32x4 v = acc[i][j];
                const float e0 = __expf(v[0] * scale), e1 = __expf(v[1] * scale);
                const float e2 = __expf(v[2] * scale), e3 = __expf(v[3] * scale);
                rs[j] += (e0 + e1) + (e2 + e3);
                us4v st = { f2bf(e0), f2bf(e1), f2bf(e2), f2bf(e3) };
                *(us4v*)((us16*)C + (size_t)n * M + mb) = st;
            }
        }
#pragma unroll
        for (int j = 0; j < 4; j++) {
            rs[j] += __shfl_xor(rs[j], 16, 64);
            rs[j] += __shfl_xor(rs[j], 32, 64);
        }
        if (quad == 0) {
#pragma unroll
            for (int j = 0; j < 4; j++)
                atomicAdd(&L[n0 + wn * 64 + j * 16 + l15], rs[j]);
        }
        return;
    }

#pragma unroll
    for (int i = 0; i < MI; i++) {
        const int mb = m0 + wm * (MI * 16) + i * 16 + quad * 4;
        float b0 = 0.f, b1 = 0.f, b2 = 0.f, b3 = 0.f;
        if (EPI == 0) {
            float4 bv4 = *(const float4*)(bias + mb);
            b0 = bv4.x; b1 = bv4.y; b2 = bv4.z; b3 = bv4.w;
        }
#pragma unroll
        for (int j = 0; j < 4; j++) {
            const int n = n0 + wn * 64 + j * 16 + l15;
            f32x4 v = acc[i][j];
            if (EPI == 3) {
                const float inv = 1.0f / L[n];
                float4 st;
                st.x = v[0] * inv; st.y = v[1] * inv;
                st.z = v[2] * inv; st.w = v[3] * inv;
                *(float4*)((float*)C + (size_t)n * M + mb) = st;
            } else {
                const float bn = (EPI == 1) ? bias[n] : 0.0f;
                us4v st = { f2bf(v[0] + b0 + bn), f2bf(v[1] + b1 + bn),
                            f2bf(v[2] + b2 + bn), f2bf(v[3] + b3 + bn) };
                *(us4v*)((us16*)C + (size_t)n * M + mb) = st;
            }
        }
    }
}

// strip swizzle: lin in [0, gx*gy), strips of 4 m-panels (gx % 4 == 0).
// Same-XCD subsequences (stride 8) stay within a 4-A-panel strip -> L2 reuse.
__device__ __forceinline__ void strip_xy(int lin, int gy, int& x, int& y) {
    const int within = lin & (4 * gy - 1);   // gy is pow2
    x = (lin / (4 * gy)) * 4 + (within & 3);
    y = within >> 2;
}

// ---------------------------------------------------------------------------
// prep: id<2048 -> transpose x [B][D][S] f32 -> XT [B][S][D] bf16 (64x64 tile)
//       id>=2048 -> convert Wq/Wk/Wv f32 -> Wb bf16 [3][1024][1024]
// ---------------------------------------------------------------------------
__global__ __launch_bounds__(256)
void prep(const float* __restrict__ x, us16* __restrict__ xt,
          const float* __restrict__ wq, const float* __restrict__ wk,
          const float* __restrict__ wv, us16* __restrict__ wb) {
    __shared__ us16 tile[64 * 65];
    const int id = blockIdx.x;
    const int t = threadIdx.x;
    if (id < 2048) {
        const int s0 = (id & 31) * 64, d0 = ((id >> 5) & 15) * 64, b = id >> 9;
        const float* xp = x + ((size_t)b * 1024 + d0) * 2048 + s0;
        const int r = t >> 4, c4 = t & 15;
#pragma unroll
        for (int i = 0; i < 4; i++) {
            float4 v = *(const float4*)(xp + (size_t)(r + 16 * i) * 2048 + c4 * 4);
            const int d = r + 16 * i;
            tile[(c4 * 4 + 0) * 65 + d] = f2bf(v.x);
            tile[(c4 * 4 + 1) * 65 + d] = f2bf(v.y);
            tile[(c4 * 4 + 2) * 65 + d] = f2bf(v.z);
            tile[(c4 * 4 + 3) * 65 + d] = f2bf(v.w);
        }
        __syncthreads();
        us16* op = xt + ((size_t)b * 2048 + s0) * 1024 + d0;
#pragma unroll
        for (int i = 0; i < 2; i++) {
            const int u = t + 256 * i;
            const int s = u >> 3, c8 = u & 7;
            us8 o;
#pragma unroll
            for (int j = 0; j < 8; j++) o[j] = tile[s * 65 + c8 * 8 + j];
            *(us8*)(op + (size_t)s * 1024 + c8 * 8) = o;
        }
    } else {
        const int cid = id - 2048;                  // 0..3071
        const int mb = cid >> 10;
        const float* src = (mb == 0) ? wq : (mb == 1) ? wk : wv;
        const size_t off = ((size_t)(cid & 1023) * 256 + t) * 4;
        float4 v = *(const float4*)(src + off);
        us4v o = { f2bf(v.x), f2bf(v.y), f2bf(v.z), f2bf(v.w) };
        *(us4v*)(wb + (size_t)mb * 1048576 + off) = o;
    }
}

// ---------------------------------------------------------------------------
// qkv: one dispatch, 512 blocks of 512 threads.
//  id < 256 : Q/K at 256x256. z=id>>5 (0..3 Q, 4..7 K), grid 4(m=e) x 8(n=s)
//  id >= 256: V   at 128x256. z=(id-256)>>6, grid 16(m=s) x 4(n=e) -> VT [e][s]
// ---------------------------------------------------------------------------
__global__ __launch_bounds__(512)
void qkv(const us16* __restrict__ Wb, const us16* __restrict__ XT,
         us16* __restrict__ Qb, us16* __restrict__ Kb, us16* __restrict__ VT,
         const float* __restrict__ bq, const float* __restrict__ bk,
         const float* __restrict__ bv) {
    __shared__ __align__(16) us16 lds[65536];   // 128 KiB: 2 x (256+256)x64
    const int id = blockIdx.x;
    const long long sXT = 2097152;   // S*D
    if (id < 256) {
        const int z = id >> 5, zz = z & 3;
        const bool isK = z >= 4;
        int x, y; strip_xy(id & 31, 8, x, y);
        const us16* A = Wb + (isK ? 1048576 : 0);
        const us16* B = XT + (size_t)zz * sXT;
        us16* C = (isK ? Kb : Qb) + (size_t)zz * sXT;
        gemm_core<0, 8>(A, B, (void*)C, isK ? bk : bq, nullptr, 1024, 1024, x, y, lds);
    } else {
        const int id2 = id - 256;
        const int z = id2 >> 6;
        int x, y; strip_xy(id2 & 63, 4, x, y);
        gemm_core<1, 4>(XT + (size_t)z * sXT, Wb + 2097152,
                        (void*)(VT + (size_t)z * sXT), bv, nullptr,
                        2048, 1024, x, y, lds);
    }
}

// ---------------------------------------------------------------------------
// scores: P~[b][s][t] = exp(q_s.k_t/32), plus L[b][s] = sum_t P~ (atomics)
// A=K (m=t), B=Q (n=s), 256x256 tile, grid (8,8,4) = 256 blocks
// ---------------------------------------------------------------------------
__global__ __launch_bounds__(512)
void scores_k(const us16* __restrict__ Kb, const us16* __restrict__ Qb,
              us16* __restrict__ Sb, float* __restrict__ L) {
    __shared__ __align__(16) us16 lds[65536];
    const long long sXT = 2097152, sSS = 4194304;
    const int z = blockIdx.z;
    int x, y; strip_xy(blockIdx.x + 8 * blockIdx.y, 8, x, y);
    gemm_core<2, 8>(Kb + (size_t)z * sXT, Qb + (size_t)z * sXT,
                    (void*)(Sb + (size_t)z * sSS), nullptr, L + z * 2048,
                    2048, 1024, x, y, lds);
}

// ---------------------------------------------------------------------------
// out: out[b][s][e] = (sum_t P~[s][t] v[t][e]) / L[b][s]
// A=VT (m=e), B=P~ (n=s), 128x256 tile, grid (8,8,4) = 256 blocks
// ---------------------------------------------------------------------------
__global__ __launch_bounds__(512)
void out_k(const us16* __restrict__ VT, const us16* __restrict__ Sb,
           float* __restrict__ L, float* __restrict__ out) {
    __shared__ __align__(16) us16 lds[49152];   // 96 KiB: 2 x (128+256)x64
    const long long sXT = 2097152, sSS = 4194304;
    const int z = blockIdx.z;
    int x, y; strip_xy(blockIdx.x + 8 * blockIdx.y, 8, x, y);
    gemm_core<3, 4>(VT + (size_t)z * sXT, Sb + (size_t)z * sSS,
                    (void*)(out + (size_t)z * sXT), nullptr, L + z * 2048,
                    1024, 2048, x, y, lds);
}

// ---------------------------------------------------------------------------
extern "C" void kernel_launch(void* const* d_in, const int* in_sizes, int n_in,
                              void* d_out, int out_size, void* d_ws, size_t ws_size,
                              hipStream_t stream) {
    const float* x  = (const float*)d_in[0];
    const float* Wq = (const float*)d_in[1];
    const float* bq = (const float*)d_in[2];
    const float* Wk = (const float*)d_in[3];
    const float* bk = (const float*)d_in[4];
    const float* Wv = (const float*)d_in[5];
    const float* bv = (const float*)d_in[6];
    float* out = (float*)d_out;
    char* ws = (char*)d_ws;

    const size_t SZ = 16777216;   // B*S*D bf16
    us16* Qb = (us16*)(ws);
    us16* Kb = (us16*)(ws + SZ);
    us16* VT = (us16*)(ws + 2 * SZ);            // [B][D][S]
    us16* XT = (us16*)(ws + 3 * SZ);            // [B][S][D]
    us16* Wb = (us16*)(ws + 4 * SZ);            // [3][1024][1024]
    us16* Sb = (us16*)(ws + 3 * SZ);            // P~ [B][S][S], aliases dead XT/Wb
    float* Lb = (float*)(ws + 5 * SZ);          // L [B][S] fp32 at 80 MiB

    hipMemsetAsync(Lb, 0, 4 * 2048 * sizeof(float), stream);
    prep<<<dim3(5120, 1, 1), dim3(256, 1, 1), 0, stream>>>(x, XT, Wq, Wk, Wv, Wb);
    qkv<<<dim3(512, 1, 1), dim3(512, 1, 1), 0, stream>>>(Wb, XT, Qb, Kb, VT, bq, bk, bv);
    scores_k<<<dim3(8, 8, 4), dim3(512, 1, 1), 0, stream>>>(Kb, Qb, Sb, Lb);
    out_k<<<dim3(8, 8, 4), dim3(512, 1, 1), 0, stream>>>(VT, Sb, Lb, out);
}

// Round 3
// 233.356 us; speedup vs baseline: 1.0815x; 1.0280x over previous
//
#include <hip/hip_runtime.h>
#include <stdint.h>

typedef unsigned short us16;
typedef unsigned short us8  __attribute__((ext_vector_type(8)));
typedef unsigned short us4v __attribute__((ext_vector_type(4)));
typedef __bf16         bf16x8 __attribute__((ext_vector_type(8)));
typedef float          f32x4  __attribute__((ext_vector_type(4)));

__device__ __forceinline__ us16 f2bf(float f) {
    union { float f; unsigned int u; } c; c.f = f;
    unsigned int u = (c.u + 0x7fffu + ((c.u >> 16) & 1u)) >> 16;
    return (us16)u;
}

// async global->LDS, 16 B per lane; LDS dest = wave-uniform base + lane*16
__device__ __forceinline__ void async16(const us16* g, us16* l) {
    __builtin_amdgcn_global_load_lds(
        (const __attribute__((address_space(1))) unsigned int*)g,
        (__attribute__((address_space(3))) unsigned int*)l,
        16, 0, 0);
}

// ---------------------------------------------------------------------------
// GEMM core v4: C[n][m] = sum_k A[m][k]*B[n][k], ldC = M.
//  Tile BM x 256 (BM = MI*32), BK = 64, 8 waves (2 M x 4 N), 512 threads.
//  LDS: 2 whole-tile buffers; rows 128 B, phys chunk = logical ^ (row&7)
//  (proven 0-conflict swizzle, both-sides).
//  m201-order schedule: per tile
//    vmcnt(0) [waits loads issued a FULL TILE ago -> ~free, not a drain]
//    entry barrier  [buffer-free + buffer-valid for all waves, by ordering]
//    stage tile t+1 (8 calls) ; read B frags + phase-0 A frags
//    4 x { barrier ; lgkmcnt(0)+sched_barrier(0) ; setprio(1) 16 MFMA
//          setprio(0) ; read next phase's A frags }
//  Reads always sit on the far side of a barrier from their MFMAs, so LDS
//  latency drains under barrier-wait / sibling-wave MFMA (T3 role-split,
//  which is what makes setprio pay).
// EPI: 0 bf16 store + bias[m] | 1 bf16 store + bias[n]
//      2 bf16 store of exp(acc/32) + atomicAdd row sums into L[n]
//      3 f32 store of acc * (1/L[n])
// ---------------------------------------------------------------------------
template <int EPI, int MI>
__device__ __forceinline__ void gemm_core(
        const us16* __restrict__ A, const us16* __restrict__ B,
        void* __restrict__ C, const float* __restrict__ bias,
        float* __restrict__ L,
        int M, int K, int x, int y, us16* lds) {
    constexpr int BM     = MI * 32;
    constexpr int BOFF   = BM * 64;            // B region offset (elems)
    constexpr int BUF    = (BM + 256) * 64;    // elems per buffer
    constexpr int ACALLS = BM / 64;            // 8KB stage calls for A
    constexpr int PMI    = MI / 4;             // A frag-rows per phase

    const int tid  = threadIdx.x;
    const int lane = tid & 63, wid = tid >> 6;
    const int l15  = lane & 15, quad = lane >> 4;
    const int wm   = wid >> 2, wn = wid & 3;   // 2 x 4 wave grid
    const int m0   = x * BM, n0 = y * 256;

    // staging: call covers 64 rows; thread t -> row t>>3, stored chunk t&7,
    // global chunk pre-swizzled (t&7)^(row&7). LDS dest linear = base+t*16B.
    const int srow = tid >> 3;
    const int sc   = ((tid & 7) ^ (srow & 7)) * 8;
    const us16* Ag = A + (size_t)(m0 + srow) * K + sc;
    const us16* Bg = B + (size_t)(n0 + srow) * K + sc;
    const int sl   = tid * 8;                  // elem offset within call

    f32x4 acc[MI][4] = {};
    const int NT = K >> 6;

    // prologue: stage tile 0 into buf 0
#pragma unroll
    for (int c = 0; c < ACALLS; c++) async16(Ag + (size_t)(c * 64) * K, lds + c * 4096 + sl);
#pragma unroll
    for (int c = 0; c < 4; c++)      async16(Bg + (size_t)(c * 64) * K, lds + BOFF + c * 4096 + sl);

    for (int t = 0; t < NT; t++) {
        const us16* cur = lds + (t & 1) * BUF;
        // tile t's loads were issued at the top of tile t-1 (~4 phases ago):
        // this wait is on tile-old loads, not a fresh-load drain.
        asm volatile("s_waitcnt vmcnt(0)" ::: "memory");
        __builtin_amdgcn_sched_barrier(0);
        __builtin_amdgcn_s_barrier();   // entry: prev buf free + cur buf valid
        __builtin_amdgcn_sched_barrier(0);

        // stage all of tile t+1 into the other buffer (in flight across tile)
        if (t + 1 < NT) {
            us16* nxt = lds + ((t + 1) & 1) * BUF;
            const size_t ko = (size_t)(t + 1) * 64;
#pragma unroll
            for (int c = 0; c < ACALLS; c++) async16(Ag + (size_t)(c * 64) * K + ko, nxt + c * 4096 + sl);
#pragma unroll
            for (int c = 0; c < 4; c++)      async16(Bg + (size_t)(c * 64) * K + ko, nxt + BOFF + c * 4096 + sl);
        }

        // B fragments (whole tile) + phase-0 A fragments: issued BEFORE the
        // phase-0 barrier so their latency drains under the barrier wait.
        bf16x8 bf[4][2];
#pragma unroll
        for (int nj = 0; nj < 4; nj++) {
            const int rb = wn * 64 + nj * 16 + l15;
#pragma unroll
            for (int ks = 0; ks < 2; ks++)
                bf[nj][ks] = *(const bf16x8*)(cur + BOFF + rb * 64 + ((ks * 4 + quad) ^ (rb & 7)) * 8);
        }
        bf16x8 af[PMI][2];
#pragma unroll
        for (int i = 0; i < PMI; i++) {
            const int ra = wm * (MI * 16) + i * 16 + l15;
#pragma unroll
            for (int ks = 0; ks < 2; ks++)
                af[i][ks] = *(const bf16x8*)(cur + ra * 64 + ((ks * 4 + quad) ^ (ra & 7)) * 8);
        }

#pragma unroll
        for (int p = 0; p < 4; p++) {
            __builtin_amdgcn_sched_barrier(0);   // keep reads above the barrier
            __builtin_amdgcn_s_barrier();
            asm volatile("s_waitcnt lgkmcnt(0)" ::: "memory");
            __builtin_amdgcn_sched_barrier(0);   // rule 18: MFMA must not hoist
            __builtin_amdgcn_s_setprio(1);
#pragma unroll
            for (int ks = 0; ks < 2; ks++)
#pragma unroll
                for (int i = 0; i < PMI; i++)
#pragma unroll
                    for (int nj = 0; nj < 4; nj++)
                        acc[p * PMI + i][nj] = __builtin_amdgcn_mfma_f32_16x16x32_bf16(
                            af[i][ks], bf[nj][ks], acc[p * PMI + i][nj], 0, 0, 0);
            __builtin_amdgcn_s_setprio(0);
            if (p < 3) {
                // next phase's A fragments: latency hides under next barrier
#pragma unroll
                for (int i = 0; i < PMI; i++) {
                    const int ra = wm * (MI * 16) + ((p + 1) * PMI + i) * 16 + l15;
#pragma unroll
                    for (int ks = 0; ks < 2; ks++)
                        af[i][ks] = *(const bf16x8*)(cur + ra * 64 + ((ks * 4 + quad) ^ (ra & 7)) * 8);
                }
            }
        }
    }

    if (EPI == 2) {
        const float scale = 0.03125f;
        float rs[4] = {0.f, 0.f, 0.f, 0.f};
#pragma unroll
        for (int i = 0; i < MI; i++) {
            const int mb = m0 + wm * (MI * 16) + i * 16 + quad * 4;
#pragma unroll
            for (int j = 0; j < 4; j++) {
                const int n = n0 + wn * 64 + j * 16 + l15;
                f32x4 v = acc[i][j];
                const float e0 = __expf(v[0] * scale), e1 = __expf(v[1] * scale);
                const float e2 = __expf(v[2] * scale), e3 = __expf(v[3] * scale);
                rs[j] += (e0 + e1) + (e2 + e3);
                us4v st = { f2bf(e0), f2bf(e1), f2bf(e2), f2bf(e3) };
                *(us4v*)((us16*)C + (size_t)n * M + mb) = st;
            }
        }
#pragma unroll
        for (int j = 0; j < 4; j++) {
            rs[j] += __shfl_xor(rs[j], 16, 64);
            rs[j] += __shfl_xor(rs[j], 32, 64);
        }
        if (quad == 0) {
#pragma unroll
            for (int j = 0; j < 4; j++)
                atomicAdd(&L[n0 + wn * 64 + j * 16 + l15], rs[j]);
        }
        return;
    }

#pragma unroll
    for (int i = 0; i < MI; i++) {
        const int mb = m0 + wm * (MI * 16) + i * 16 + quad * 4;
        float b0 = 0.f, b1 = 0.f, b2 = 0.f, b3 = 0.f;
        if (EPI == 0) {
            float4 bv4 = *(const float4*)(bias + mb);
            b0 = bv4.x; b1 = bv4.y; b2 = bv4.z; b3 = bv4.w;
        }
#pragma unroll
        for (int j = 0; j < 4; j++) {
            const int n = n0 + wn * 64 + j * 16 + l15;
            f32x4 v = acc[i][j];
            if (EPI == 3) {
                const float inv = 1.0f / L[n];
                float4 st;
                st.x = v[0] * inv; st.y = v[1] * inv;
                st.z = v[2] * inv; st.w = v[3] * inv;
                *(float4*)((float*)C + (size_t)n * M + mb) = st;
            } else {
                const float bn = (EPI == 1) ? bias[n] : 0.0f;
                us4v st = { f2bf(v[0] + b0 + bn), f2bf(v[1] + b1 + bn),
                            f2bf(v[2] + b2 + bn), f2bf(v[3] + b3 + bn) };
                *(us4v*)((us16*)C + (size_t)n * M + mb) = st;
            }
        }
    }
}

// strip swizzle: lin in [0, gx*gy), strips of 4 m-panels (gx % 4 == 0).
// Same-XCD subsequences (stride 8) stay within a 4-A-panel strip -> L2 reuse.
__device__ __forceinline__ void strip_xy(int lin, int gy, int& x, int& y) {
    const int within = lin & (4 * gy - 1);   // gy is pow2
    x = (lin / (4 * gy)) * 4 + (within & 3);
    y = within >> 2;
}

// ---------------------------------------------------------------------------
// prep: id<2048 -> transpose x [B][D][S] f32 -> XT [B][S][D] bf16 (64x64 tile)
//       id>=2048 -> convert Wq/Wk/Wv f32 -> Wb bf16 [3][1024][1024]
// ---------------------------------------------------------------------------
__global__ __launch_bounds__(256)
void prep(const float* __restrict__ x, us16* __restrict__ xt,
          const float* __restrict__ wq, const float* __restrict__ wk,
          const float* __restrict__ wv, us16* __restrict__ wb) {
    __shared__ us16 tile[64 * 65];
    const int id = blockIdx.x;
    const int t = threadIdx.x;
    if (id < 2048) {
        const int s0 = (id & 31) * 64, d0 = ((id >> 5) & 15) * 64, b = id >> 9;
        const float* xp = x + ((size_t)b * 1024 + d0) * 2048 + s0;
        const int r = t >> 4, c4 = t & 15;
#pragma unroll
        for (int i = 0; i < 4; i++) {
            float4 v = *(const float4*)(xp + (size_t)(r + 16 * i) * 2048 + c4 * 4);
            const int d = r + 16 * i;
            tile[(c4 * 4 + 0) * 65 + d] = f2bf(v.x);
            tile[(c4 * 4 + 1) * 65 + d] = f2bf(v.y);
            tile[(c4 * 4 + 2) * 65 + d] = f2bf(v.z);
            tile[(c4 * 4 + 3) * 65 + d] = f2bf(v.w);
        }
        __syncthreads();
        us16* op = xt + ((size_t)b * 2048 + s0) * 1024 + d0;
#pragma unroll
        for (int i = 0; i < 2; i++) {
            const int u = t + 256 * i;
            const int s = u >> 3, c8 = u & 7;
            us8 o;
#pragma unroll
            for (int j = 0; j < 8; j++) o[j] = tile[s * 65 + c8 * 8 + j];
            *(us8*)(op + (size_t)s * 1024 + c8 * 8) = o;
        }
    } else {
        const int cid = id - 2048;                  // 0..3071
        const int mb = cid >> 10;
        const float* src = (mb == 0) ? wq : (mb == 1) ? wk : wv;
        const size_t off = ((size_t)(cid & 1023) * 256 + t) * 4;
        float4 v = *(const float4*)(src + off);
        us4v o = { f2bf(v.x), f2bf(v.y), f2bf(v.z), f2bf(v.w) };
        *(us4v*)(wb + (size_t)mb * 1048576 + off) = o;
    }
}

// ---------------------------------------------------------------------------
// qkv: one dispatch, 512 blocks of 512 threads.
//  id < 256 : Q/K at 256x256. z=id>>5 (0..3 Q, 4..7 K), grid 4(m=e) x 8(n=s)
//  id >= 256: V   at 128x256. z=(id-256)>>6, grid 16(m=s) x 4(n=e) -> VT [e][s]
// ---------------------------------------------------------------------------
__global__ __launch_bounds__(512)
void qkv(const us16* __restrict__ Wb, const us16* __restrict__ XT,
         us16* __restrict__ Qb, us16* __restrict__ Kb, us16* __restrict__ VT,
         const float* __restrict__ bq, const float* __restrict__ bk,
         const float* __restrict__ bv) {
    __shared__ __align__(16) us16 lds[65536];   // 128 KiB: 2 x (256+256)x64
    const int id = blockIdx.x;
    const long long sXT = 2097152;   // S*D
    if (id < 256) {
        const int z = id >> 5, zz = z & 3;
        const bool isK = z >= 4;
        int x, y; strip_xy(id & 31, 8, x, y);
        const us16* A = Wb + (isK ? 1048576 : 0);
        const us16* B = XT + (size_t)zz * sXT;
        us16* C = (isK ? Kb : Qb) + (size_t)zz * sXT;
        gemm_core<0, 8>(A, B, (void*)C, isK ? bk : bq, nullptr, 1024, 1024, x, y, lds);
    } else {
        const int id2 = id - 256;
        const int z = id2 >> 6;
        int x, y; strip_xy(id2 & 63, 4, x, y);
        gemm_core<1, 4>(XT + (size_t)z * sXT, Wb + 2097152,
                        (void*)(VT + (size_t)z * sXT), bv, nullptr,
                        2048, 1024, x, y, lds);
    }
}

// ---------------------------------------------------------------------------
// scores: P~[b][s][t] = exp(q_s.k_t/32), plus L[b][s] = sum_t P~ (atomics)
// A=K (m=t), B=Q (n=s), 256x256 tile, grid (8,8,4) = 256 blocks
// ---------------------------------------------------------------------------
__global__ __launch_bounds__(512)
void scores_k(const us16* __restrict__ Kb, const us16* __restrict__ Qb,
              us16* __restrict__ Sb, float* __restrict__ L) {
    __shared__ __align__(16) us16 lds[65536];
    const long long sXT = 2097152, sSS = 4194304;
    const int z = blockIdx.z;
    int x, y; strip_xy(blockIdx.x + 8 * blockIdx.y, 8, x, y);
    gemm_core<2, 8>(Kb + (size_t)z * sXT, Qb + (size_t)z * sXT,
                    (void*)(Sb + (size_t)z * sSS), nullptr, L + z * 2048,
                    2048, 1024, x, y, lds);
}

// ---------------------------------------------------------------------------
// out: out[b][s][e] = (sum_t P~[s][t] v[t][e]) / L[b][s]
// A=VT (m=e), B=P~ (n=s), 128x256 tile, grid (8,8,4) = 256 blocks
// ---------------------------------------------------------------------------
__global__ __launch_bounds__(512)
void out_k(const us16* __restrict__ VT, const us16* __restrict__ Sb,
           float* __restrict__ L, float* __restrict__ out) {
    __shared__ __align__(16) us16 lds[49152];   // 96 KiB: 2 x (128+256)x64
    const long long sXT = 2097152, sSS = 4194304;
    const int z = blockIdx.z;
    int x, y; strip_xy(blockIdx.x + 8 * blockIdx.y, 8, x, y);
    gemm_core<3, 4>(VT + (size_t)z * sXT, Sb + (size_t)z * sSS,
                    (void*)(out + (size_t)z * sXT), nullptr, L + z * 2048,
                    1024, 2048, x, y, lds);
}

// ---------------------------------------------------------------------------
extern "C" void kernel_launch(void* const* d_in, const int* in_sizes, int n_in,
                              void* d_out, int out_size, void* d_ws, size_t ws_size,
                              hipStream_t stream) {
    const float* x  = (const float*)d_in[0];
    const float* Wq = (const float*)d_in[1];
    const float* bq = (const float*)d_in[2];
    const float* Wk = (const float*)d_in[3];
    const float* bk = (const float*)d_in[4];
    const float* Wv = (const float*)d_in[5];
    const float* bv = (const float*)d_in[6];
    float* out = (float*)d_out;
    char* ws = (char*)d_ws;

    const size_t SZ = 16777216;   // B*S*D bf16
    us16* Qb = (us16*)(ws);
    us16* Kb = (us16*)(ws + SZ);
    us16* VT = (us16*)(ws + 2 * SZ);            // [B][D][S]
    us16* XT = (us16*)(ws + 3 * SZ);            // [B][S][D]
    us16* Wb = (us16*)(ws + 4 * SZ);            // [3][1024][1024]
    us16* Sb = (us16*)(ws + 3 * SZ);            // P~ [B][S][S], aliases dead XT/Wb
    float* Lb = (float*)(ws + 5 * SZ);          // L [B][S] fp32 at 80 MiB

    hipMemsetAsync(Lb, 0, 4 * 2048 * sizeof(float), stream);
    prep<<<dim3(5120, 1, 1), dim3(256, 1, 1), 0, stream>>>(x, XT, Wq, Wk, Wv, Wb);
    qkv<<<dim3(512, 1, 1), dim3(512, 1, 1), 0, stream>>>(Wb, XT, Qb, Kb, VT, bq, bk, bv);
    scores_k<<<dim3(8, 8, 4), dim3(512, 1, 1), 0, stream>>>(Kb, Qb, Sb, Lb);
    out_k<<<dim3(8, 8, 4), dim3(512, 1, 1), 0, stream>>>(VT, Sb, Lb, out);
}

// Round 4
// 222.685 us; speedup vs baseline: 1.1333x; 1.0479x over previous
//
#include <hip/hip_runtime.h>
#include <stdint.h>

typedef unsigned short us16;
typedef unsigned short us8  __attribute__((ext_vector_type(8)));
typedef unsigned short us4v __attribute__((ext_vector_type(4)));
typedef __bf16         bf16x8 __attribute__((ext_vector_type(8)));
typedef float          f32x4  __attribute__((ext_vector_type(4)));

__device__ __forceinline__ us16 f2bf(float f) {
    union { float f; unsigned int u; } c; c.f = f;
    unsigned int u = (c.u + 0x7fffu + ((c.u >> 16) & 1u)) >> 16;
    return (us16)u;
}

// async global->LDS, 16 B per lane; LDS dest = wave-uniform base + lane*16
__device__ __forceinline__ void async16(const us16* g, us16* l) {
    __builtin_amdgcn_global_load_lds(
        (const __attribute__((address_space(1))) unsigned int*)g,
        (__attribute__((address_space(3))) unsigned int*)l,
        16, 0, 0);
}

// ---------------------------------------------------------------------------
// GEMM core v5: C[n][m] = sum_k A[m][k]*B[n][k], ldC = M.
//  Tile BM x 256 (BM = MI*32), BK = 64, 8 waves (2 M x 4 N), 512 threads.
//  LDS: 2 whole-tile buffers; rows 128 B, phys chunk = logical ^ (row&7)
//  (proven 0-conflict swizzle, both-sides).
//  Schedule: ONE __syncthreads per K-tile (its implicit vmcnt(0) waits loads
//  issued a full tile earlier -> free). No intra-tile barriers/fences at all:
//  after the entry sync the whole buffer is valid, so the 4 MFMA phases need
//  no synchronization. A-fragments for phase p+1 are read BEFORE phase p's
//  MFMA cluster so the LDS port drains reads while the matrix pipe runs
//  (they were fully serialized by the old per-phase barrier lockstep).
//  Compiler inserts fine-grained lgkmcnt between reads and consuming MFMAs.
//  Buffer safety: buf b is staged in tile t (b=(t+1)&1) and last read in
//  tile t-1; all those reads precede their wave's entry sync of tile t.
// EPI: 0 bf16 store + bias[m] | 1 bf16 store + bias[n]
//      2 bf16 store of exp(acc/32) + atomicAdd row sums into L[n]
//      3 f32 store of acc * (1/L[n])
// ---------------------------------------------------------------------------
template <int EPI, int MI>
__device__ __forceinline__ void gemm_core(
        const us16* __restrict__ A, const us16* __restrict__ B,
        void* __restrict__ C, const float* __restrict__ bias,
        float* __restrict__ L,
        int M, int K, int x, int y, us16* lds) {
    constexpr int BM     = MI * 32;
    constexpr int BOFF   = BM * 64;            // B region offset (elems)
    constexpr int BUF    = (BM + 256) * 64;    // elems per buffer
    constexpr int ACALLS = BM / 64;            // 8KB stage calls for A
    constexpr int PMI    = MI / 4;             // A frag-rows per phase

    const int tid  = threadIdx.x;
    const int lane = tid & 63, wid = tid >> 6;
    const int l15  = lane & 15, quad = lane >> 4;
    const int wm   = wid >> 2, wn = wid & 3;   // 2 x 4 wave grid
    const int m0   = x * BM, n0 = y * 256;

    // staging: call covers 64 rows; thread t -> row t>>3, stored chunk t&7,
    // global chunk pre-swizzled (t&7)^(row&7). LDS dest linear = base+t*16B.
    const int srow = tid >> 3;
    const int sc   = ((tid & 7) ^ (srow & 7)) * 8;
    const us16* Ag = A + (size_t)(m0 + srow) * K + sc;
    const us16* Bg = B + (size_t)(n0 + srow) * K + sc;
    const int sl   = tid * 8;                  // elem offset within call

    f32x4 acc[MI][4] = {};
    const int NT = K >> 6;

    // prologue: stage tile 0 into buf 0
#pragma unroll
    for (int c = 0; c < ACALLS; c++) async16(Ag + (size_t)(c * 64) * K, lds + c * 4096 + sl);
#pragma unroll
    for (int c = 0; c < 4; c++)      async16(Bg + (size_t)(c * 64) * K, lds + BOFF + c * 4096 + sl);

    for (int t = 0; t < NT; t++) {
        const us16* cur = lds + (t & 1) * BUF;
        // entry sync: implicit vmcnt(0) waits tile t's loads (issued a full
        // tile ago -> ~free) and establishes buf(t) valid / buf(t^1) free.
        __syncthreads();

        // stage all of tile t+1 (in flight until next sync)
        if (t + 1 < NT) {
            us16* nxt = lds + ((t + 1) & 1) * BUF;
            const size_t ko = (size_t)(t + 1) * 64;
#pragma unroll
            for (int c = 0; c < ACALLS; c++) async16(Ag + (size_t)(c * 64) * K + ko, nxt + c * 4096 + sl);
#pragma unroll
            for (int c = 0; c < 4; c++)      async16(Bg + (size_t)(c * 64) * K + ko, nxt + BOFF + c * 4096 + sl);
        }

        // B fragments (whole tile) + phase-0 A fragments
        bf16x8 bf[4][2];
#pragma unroll
        for (int nj = 0; nj < 4; nj++) {
            const int rb = wn * 64 + nj * 16 + l15;
#pragma unroll
            for (int ks = 0; ks < 2; ks++)
                bf[nj][ks] = *(const bf16x8*)(cur + BOFF + rb * 64 + ((ks * 4 + quad) ^ (rb & 7)) * 8);
        }
        bf16x8 af[2][PMI][2];
#pragma unroll
        for (int i = 0; i < PMI; i++) {
            const int ra = wm * (MI * 16) + i * 16 + l15;
#pragma unroll
            for (int ks = 0; ks < 2; ks++)
                af[0][i][ks] = *(const bf16x8*)(cur + ra * 64 + ((ks * 4 + quad) ^ (ra & 7)) * 8);
        }

#pragma unroll
        for (int p = 0; p < 4; p++) {
            // prefetch NEXT phase's A fragments before this phase's MFMAs:
            // LDS port services these while the matrix pipe runs phase p.
            if (p < 3) {
#pragma unroll
                for (int i = 0; i < PMI; i++) {
                    const int ra = wm * (MI * 16) + ((p + 1) * PMI + i) * 16 + l15;
#pragma unroll
                    for (int ks = 0; ks < 2; ks++)
                        af[(p + 1) & 1][i][ks] = *(const bf16x8*)(cur + ra * 64 + ((ks * 4 + quad) ^ (ra & 7)) * 8);
                }
            }
            __builtin_amdgcn_s_setprio(1);
#pragma unroll
            for (int ks = 0; ks < 2; ks++)
#pragma unroll
                for (int i = 0; i < PMI; i++)
#pragma unroll
                    for (int nj = 0; nj < 4; nj++)
                        acc[p * PMI + i][nj] = __builtin_amdgcn_mfma_f32_16x16x32_bf16(
                            af[p & 1][i][ks], bf[nj][ks], acc[p * PMI + i][nj], 0, 0, 0);
            __builtin_amdgcn_s_setprio(0);
        }
    }

    if (EPI == 2) {
        const float scale = 0.03125f;
        float rs[4] = {0.f, 0.f, 0.f, 0.f};
#pragma unroll
        for (int i = 0; i < MI; i++) {
            const int mb = m0 + wm * (MI * 16) + i * 16 + quad * 4;
#pragma unroll
            for (int j = 0; j < 4; j++) {
                const int n = n0 + wn * 64 + j * 16 + l15;
                f32x4 v = acc[i][j];
                const float e0 = __expf(v[0] * scale), e1 = __expf(v[1] * scale);
                const float e2 = __expf(v[2] * scale), e3 = __expf(v[3] * scale);
                rs[j] += (e0 + e1) + (e2 + e3);
                us4v st = { f2bf(e0), f2bf(e1), f2bf(e2), f2bf(e3) };
                *(us4v*)((us16*)C + (size_t)n * M + mb) = st;
            }
        }
#pragma unroll
        for (int j = 0; j < 4; j++) {
            rs[j] += __shfl_xor(rs[j], 16, 64);
            rs[j] += __shfl_xor(rs[j], 32, 64);
        }
        if (quad == 0) {
#pragma unroll
            for (int j = 0; j < 4; j++)
                atomicAdd(&L[n0 + wn * 64 + j * 16 + l15], rs[j]);
        }
        return;
    }

#pragma unroll
    for (int i = 0; i < MI; i++) {
        const int mb = m0 + wm * (MI * 16) + i * 16 + quad * 4;
        float b0 = 0.f, b1 = 0.f, b2 = 0.f, b3 = 0.f;
        if (EPI == 0) {
            float4 bv4 = *(const float4*)(bias + mb);
            b0 = bv4.x; b1 = bv4.y; b2 = bv4.z; b3 = bv4.w;
        }
#pragma unroll
        for (int j = 0; j < 4; j++) {
            const int n = n0 + wn * 64 + j * 16 + l15;
            f32x4 v = acc[i][j];
            if (EPI == 3) {
                const float inv = 1.0f / L[n];
                float4 st;
                st.x = v[0] * inv; st.y = v[1] * inv;
                st.z = v[2] * inv; st.w = v[3] * inv;
                *(float4*)((float*)C + (size_t)n * M + mb) = st;
            } else {
                const float bn = (EPI == 1) ? bias[n] : 0.0f;
                us4v st = { f2bf(v[0] + b0 + bn), f2bf(v[1] + b1 + bn),
                            f2bf(v[2] + b2 + bn), f2bf(v[3] + b3 + bn) };
                *(us4v*)((us16*)C + (size_t)n * M + mb) = st;
            }
        }
    }
}

// strip swizzle: lin in [0, gx*gy), strips of 4 m-panels (gx % 4 == 0).
// Same-XCD subsequences (stride 8) stay within a 4-A-panel strip -> L2 reuse.
__device__ __forceinline__ void strip_xy(int lin, int gy, int& x, int& y) {
    const int within = lin & (4 * gy - 1);   // gy is pow2
    x = (lin / (4 * gy)) * 4 + (within & 3);
    y = within >> 2;
}

// ---------------------------------------------------------------------------
// prep: id<2048 -> transpose x [B][D][S] f32 -> XT [B][S][D] bf16 (64x64 tile)
//       id>=2048 -> convert Wq/Wk/Wv f32 -> Wb bf16 [3][1024][1024]
// ---------------------------------------------------------------------------
__global__ __launch_bounds__(256)
void prep(const float* __restrict__ x, us16* __restrict__ xt,
          const float* __restrict__ wq, const float* __restrict__ wk,
          const float* __restrict__ wv, us16* __restrict__ wb) {
    __shared__ us16 tile[64 * 65];
    const int id = blockIdx.x;
    const int t = threadIdx.x;
    if (id < 2048) {
        const int s0 = (id & 31) * 64, d0 = ((id >> 5) & 15) * 64, b = id >> 9;
        const float* xp = x + ((size_t)b * 1024 + d0) * 2048 + s0;
        const int r = t >> 4, c4 = t & 15;
#pragma unroll
        for (int i = 0; i < 4; i++) {
            float4 v = *(const float4*)(xp + (size_t)(r + 16 * i) * 2048 + c4 * 4);
            const int d = r + 16 * i;
            tile[(c4 * 4 + 0) * 65 + d] = f2bf(v.x);
            tile[(c4 * 4 + 1) * 65 + d] = f2bf(v.y);
            tile[(c4 * 4 + 2) * 65 + d] = f2bf(v.z);
            tile[(c4 * 4 + 3) * 65 + d] = f2bf(v.w);
        }
        __syncthreads();
        us16* op = xt + ((size_t)b * 2048 + s0) * 1024 + d0;
#pragma unroll
        for (int i = 0; i < 2; i++) {
            const int u = t + 256 * i;
            const int s = u >> 3, c8 = u & 7;
            us8 o;
#pragma unroll
            for (int j = 0; j < 8; j++) o[j] = tile[s * 65 + c8 * 8 + j];
            *(us8*)(op + (size_t)s * 1024 + c8 * 8) = o;
        }
    } else {
        const int cid = id - 2048;                  // 0..3071
        const int mb = cid >> 10;
        const float* src = (mb == 0) ? wq : (mb == 1) ? wk : wv;
        const size_t off = ((size_t)(cid & 1023) * 256 + t) * 4;
        float4 v = *(const float4*)(src + off);
        us4v o = { f2bf(v.x), f2bf(v.y), f2bf(v.z), f2bf(v.w) };
        *(us4v*)(wb + (size_t)mb * 1048576 + off) = o;
    }
}

// ---------------------------------------------------------------------------
// qkv: one dispatch, 512 blocks of 512 threads.
//  id < 256 : Q/K at 256x256. z=id>>5 (0..3 Q, 4..7 K), grid 4(m=e) x 8(n=s)
//  id >= 256: V   at 128x256. z=(id-256)>>6, grid 16(m=s) x 4(n=e) -> VT [e][s]
// ---------------------------------------------------------------------------
__global__ __launch_bounds__(512)
void qkv(const us16* __restrict__ Wb, const us16* __restrict__ XT,
         us16* __restrict__ Qb, us16* __restrict__ Kb, us16* __restrict__ VT,
         const float* __restrict__ bq, const float* __restrict__ bk,
         const float* __restrict__ bv) {
    __shared__ __align__(16) us16 lds[65536];   // 128 KiB: 2 x (256+256)x64
    const int id = blockIdx.x;
    const long long sXT = 2097152;   // S*D
    if (id < 256) {
        const int z = id >> 5, zz = z & 3;
        const bool isK = z >= 4;
        int x, y; strip_xy(id & 31, 8, x, y);
        const us16* A = Wb + (isK ? 1048576 : 0);
        const us16* B = XT + (size_t)zz * sXT;
        us16* C = (isK ? Kb : Qb) + (size_t)zz * sXT;
        gemm_core<0, 8>(A, B, (void*)C, isK ? bk : bq, nullptr, 1024, 1024, x, y, lds);
    } else {
        const int id2 = id - 256;
        const int z = id2 >> 6;
        int x, y; strip_xy(id2 & 63, 4, x, y);
        gemm_core<1, 4>(XT + (size_t)z * sXT, Wb + 2097152,
                        (void*)(VT + (size_t)z * sXT), bv, nullptr,
                        2048, 1024, x, y, lds);
    }
}

// ---------------------------------------------------------------------------
// scores: P~[b][s][t] = exp(q_s.k_t/32), plus L[b][s] = sum_t P~ (atomics)
// A=K (m=t), B=Q (n=s), 256x256 tile, grid (8,8,4) = 256 blocks
// ---------------------------------------------------------------------------
__global__ __launch_bounds__(512)
void scores_k(const us16* __restrict__ Kb, const us16* __restrict__ Qb,
              us16* __restrict__ Sb, float* __restrict__ L) {
    __shared__ __align__(16) us16 lds[65536];
    const long long sXT = 2097152, sSS = 4194304;
    const int z = blockIdx.z;
    int x, y; strip_xy(blockIdx.x + 8 * blockIdx.y, 8, x, y);
    gemm_core<2, 8>(Kb + (size_t)z * sXT, Qb + (size_t)z * sXT,
                    (void*)(Sb + (size_t)z * sSS), nullptr, L + z * 2048,
                    2048, 1024, x, y, lds);
}

// ---------------------------------------------------------------------------
// out: out[b][s][e] = (sum_t P~[s][t] v[t][e]) / L[b][s]
// A=VT (m=e), B=P~ (n=s), 128x256 tile, grid (8,8,4) = 256 blocks
// ---------------------------------------------------------------------------
__global__ __launch_bounds__(512)
void out_k(const us16* __restrict__ VT, const us16* __restrict__ Sb,
           float* __restrict__ L, float* __restrict__ out) {
    __shared__ __align__(16) us16 lds[49152];   // 96 KiB: 2 x (128+256)x64
    const long long sXT = 2097152, sSS = 4194304;
    const int z = blockIdx.z;
    int x, y; strip_xy(blockIdx.x + 8 * blockIdx.y, 8, x, y);
    gemm_core<3, 4>(VT + (size_t)z * sXT, Sb + (size_t)z * sSS,
                    (void*)(out + (size_t)z * sXT), nullptr, L + z * 2048,
                    1024, 2048, x, y, lds);
}

// ---------------------------------------------------------------------------
extern "C" void kernel_launch(void* const* d_in, const int* in_sizes, int n_in,
                              void* d_out, int out_size, void* d_ws, size_t ws_size,
                              hipStream_t stream) {
    const float* x  = (const float*)d_in[0];
    const float* Wq = (const float*)d_in[1];
    const float* bq = (const float*)d_in[2];
    const float* Wk = (const float*)d_in[3];
    const float* bk = (const float*)d_in[4];
    const float* Wv = (const float*)d_in[5];
    const float* bv = (const float*)d_in[6];
    float* out = (float*)d_out;
    char* ws = (char*)d_ws;

    const size_t SZ = 16777216;   // B*S*D bf16
    us16* Qb = (us16*)(ws);
    us16* Kb = (us16*)(ws + SZ);
    us16* VT = (us16*)(ws + 2 * SZ);            // [B][D][S]
    us16* XT = (us16*)(ws + 3 * SZ);            // [B][S][D]
    us16* Wb = (us16*)(ws + 4 * SZ);            // [3][1024][1024]
    us16* Sb = (us16*)(ws + 3 * SZ);            // P~ [B][S][S], aliases dead XT/Wb
    float* Lb = (float*)(ws + 5 * SZ);          // L [B][S] fp32 at 80 MiB

    hipMemsetAsync(Lb, 0, 4 * 2048 * sizeof(float), stream);
    prep<<<dim3(5120, 1, 1), dim3(256, 1, 1), 0, stream>>>(x, XT, Wq, Wk, Wv, Wb);
    qkv<<<dim3(512, 1, 1), dim3(512, 1, 1), 0, stream>>>(Wb, XT, Qb, Kb, VT, bq, bk, bv);
    scores_k<<<dim3(8, 8, 4), dim3(512, 1, 1), 0, stream>>>(Kb, Qb, Sb, Lb);
    out_k<<<dim3(8, 8, 4), dim3(512, 1, 1), 0, stream>>>(VT, Sb, Lb, out);
}